// Round 19
// baseline (592.056 us; speedup 1.0000x reference)
//
#include <hip/hip_runtime.h>
#include <hip/hip_bf16.h>
#include <math.h>

#define HID 192
#define NNODES 5184
#define NSTEPS 16

typedef float f32x4 __attribute__((ext_vector_type(4)));
typedef __bf16 bf16x8 __attribute__((ext_vector_type(8)));
typedef unsigned short ushort_t;
typedef ushort_t us8 __attribute__((ext_vector_type(8)));

__device__ __forceinline__ ushort_t f2bf(float f){
    __hip_bfloat16 h = __float2bfloat16(f);
    return __builtin_bit_cast(ushort_t, h);
}
__device__ __forceinline__ float bf2f(ushort_t u){
    return __uint_as_float(((unsigned)u) << 16);
}

#define HFI(r,c) ((r)*192 + ((c) ^ (((r)&7)<<2)))   // f32 buffer [81][192]
#define ABI(r,c) ((r)*384 + ((c) ^ (((r)&7)<<3)))   // bf16 buffer [81][384]
#define HBI(r,c) ((r)*192 + ((c) ^ (((r)&7)<<3)))   // bf16 buffer [81][192]

__device__ __forceinline__ bf16x8 ldsfrag(const ushort_t* buf, int rt, int ks, int lane){
    int r = rt*16 + (lane & 15);
    int k0 = ks*32 + ((lane >> 4) << 3);
    if (r < 81) return *(const bf16x8*)&buf[HBI(r, k0)];
    us8 z = {0,0,0,0,0,0,0,0};
    return __builtin_bit_cast(bf16x8, z);
}
__device__ __forceinline__ bf16x8 wfragN(const ushort_t* W, int ct, int nks, int ks, int lane){
    return *(const bf16x8*)&W[(size_t)(((ct*nks) + ks)*64 + lane)*8];
}

// ---------------------------------------------------------------------------
template <bool TRANSB>
__global__ __launch_bounds__(256)
void k_gemm(const float* __restrict__ A, const float* __restrict__ B,
            const float* __restrict__ bias, float biasScale,
            float* __restrict__ C, int N) {
    const int K = HID;
    __shared__ float As[64][17];
    __shared__ float Bs[16][65];
    int tid = threadIdx.x;
    int tx = tid & 15, ty = tid >> 4;
    int rowBase = blockIdx.x * 64;
    int colBase = blockIdx.y * 64;
    float acc[4][4] = {};
    for (int k0 = 0; k0 < K; k0 += 16) {
        {
            int r = tid >> 2, kk = (tid & 3) << 2;
            const float4 av = *(const float4*)&A[(size_t)(rowBase + r) * K + k0 + kk];
            As[r][kk + 0] = av.x; As[r][kk + 1] = av.y;
            As[r][kk + 2] = av.z; As[r][kk + 3] = av.w;
        }
        if (!TRANSB) {
            int kk = tid >> 4, j4 = (tid & 15) << 2;
            const float4 bv = *(const float4*)&B[(size_t)(k0 + kk) * N + colBase + j4];
            Bs[kk][j4 + 0] = bv.x; Bs[kk][j4 + 1] = bv.y;
            Bs[kk][j4 + 2] = bv.z; Bs[kk][j4 + 3] = bv.w;
        } else {
            int jj = tid >> 2, kk = (tid & 3) << 2;
            const float4 bv = *(const float4*)&B[(size_t)(colBase + jj) * K + k0 + kk];
            Bs[kk + 0][jj] = bv.x; Bs[kk + 1][jj] = bv.y;
            Bs[kk + 2][jj] = bv.z; Bs[kk + 3][jj] = bv.w;
        }
        __syncthreads();
#pragma unroll
        for (int kk = 0; kk < 16; kk++) {
            float a0 = As[ty*4+0][kk], a1 = As[ty*4+1][kk];
            float a2 = As[ty*4+2][kk], a3 = As[ty*4+3][kk];
            float b0 = Bs[kk][tx*4+0], b1 = Bs[kk][tx*4+1];
            float b2 = Bs[kk][tx*4+2], b3 = Bs[kk][tx*4+3];
            acc[0][0]+=a0*b0; acc[0][1]+=a0*b1; acc[0][2]+=a0*b2; acc[0][3]+=a0*b3;
            acc[1][0]+=a1*b0; acc[1][1]+=a1*b1; acc[1][2]+=a1*b2; acc[1][3]+=a1*b3;
            acc[2][0]+=a2*b0; acc[2][1]+=a2*b1; acc[2][2]+=a2*b2; acc[2][3]+=a2*b3;
            acc[3][0]+=a3*b0; acc[3][1]+=a3*b1; acc[3][2]+=a3*b2; acc[3][3]+=a3*b3;
        }
        __syncthreads();
    }
    float4 bb = make_float4(0.f,0.f,0.f,0.f);
    if (bias) {
        bb = *(const float4*)&bias[colBase + tx*4];
        bb.x*=biasScale; bb.y*=biasScale; bb.z*=biasScale; bb.w*=biasScale;
    }
#pragma unroll
    for (int i = 0; i < 4; i++) {
        int r = rowBase + ty*4 + i;
        float4 o;
        o.x=acc[i][0]+bb.x; o.y=acc[i][1]+bb.y; o.z=acc[i][2]+bb.z; o.w=acc[i][3]+bb.w;
        *(float4*)&C[(size_t)r * N + colBase + tx*4] = o;
    }
}

// ---------------------------------------------------------------------------
__global__ void k_prep(const float* __restrict__ W_m1, const float* __restrict__ Wfused,
                       const float* __restrict__ W_hh, const float* __restrict__ W_out,
                       const float* __restrict__ W_ih, const float* __restrict__ b_m2,
                       const float* __restrict__ b_ih,
                       ushort_t* __restrict__ Wm1b, ushort_t* __restrict__ Wr,
                       ushort_t* __restrict__ Wz, ushort_t* __restrict__ Wni,
                       ushort_t* __restrict__ Wnh, ushort_t* __restrict__ Woutb,
                       float* __restrict__ bias_f) {
    int t = blockIdx.x * 256 + threadIdx.x;
    const int n0 = 73728;
    const int n1 = n0 + 73728;
    const int n2 = n1 + 73728;
    const int n3 = n2 + 36864;
    const int n4 = n3 + 36864;
    const int n5 = n4 + 3072;
    const int n6 = n5 + 576;
    if (t < n0) {
        int idx = t;
        int e = idx & 7, lane = (idx >> 3) & 63, cs = idx >> 9;
        int ct = cs / 6, ks = cs - ct*6;
        int k = ks*32 + ((lane>>4)<<3) + e, col = ct*16 + (lane & 15);
        float v = (col < 192) ? W_m1[k*192 + col] : W_m1[(192 + k)*192 + (col - 192)];
        Wm1b[idx] = f2bf(v);
    } else if (t < n1) {
        int idx = t - n0;
        int e = idx & 7, lane = (idx >> 3) & 63, cs = idx >> 9;
        int ct = cs / 12, ks = cs - ct*12;
        int k = ks*32 + ((lane>>4)<<3) + e, col = ct*16 + (lane & 15);
        float v = (k < 192) ? Wfused[k*576 + col] : W_hh[col*192 + (k - 192)];
        Wr[idx] = f2bf(v);
    } else if (t < n2) {
        int idx = t - n1;
        int e = idx & 7, lane = (idx >> 3) & 63, cs = idx >> 9;
        int ct = cs / 12, ks = cs - ct*12;
        int k = ks*32 + ((lane>>4)<<3) + e, col = ct*16 + (lane & 15);
        float v = (k < 192) ? Wfused[k*576 + 192 + col] : W_hh[(192 + col)*192 + (k - 192)];
        Wz[idx] = f2bf(v);
    } else if (t < n3) {
        int idx = t - n2;
        int e = idx & 7, lane = (idx >> 3) & 63, cs = idx >> 9;
        int ct = cs / 6, ks = cs - ct*6;
        int k = ks*32 + ((lane>>4)<<3) + e, col = ct*16 + (lane & 15);
        Wni[idx] = f2bf(Wfused[k*576 + 384 + col]);
    } else if (t < n4) {
        int idx = t - n3;
        int e = idx & 7, lane = (idx >> 3) & 63, cs = idx >> 9;
        int ct = cs / 6, ks = cs - ct*6;
        int k = ks*32 + ((lane>>4)<<3) + e, col = ct*16 + (lane & 15);
        Wnh[idx] = f2bf(W_hh[(384 + col)*192 + k]);
    } else if (t < n5) {
        int idx = t - n4;
        int e = idx & 7, lane = (idx >> 3) & 63, ks = idx >> 9;
        int k = ks*32 + ((lane>>4)<<3) + e, col = lane & 15;
        Woutb[idx] = (col < 9) ? f2bf(W_out[k*9 + col]) : (ushort_t)0;
    } else if (t < n6) {
        int n = t - n5;
        float s = 0.f;
        for (int m = 0; m < 192; m++) s += b_m2[m] * W_ih[n*192 + m];
        bias_f[n] = 20.f * s + b_ih[n];
    }
}

__global__ void k_zero(int* p){ p[threadIdx.x] = 0; }

// GRU unit with fused LN partial stats (16-lane shfl, transient regs only).
template<int NR>
__device__ __forceinline__ void gru_unit(
    const ushort_t* Rb, const ushort_t* hb, float* hcf, float2* spart,
    const float* biasfs, const float* bhhs,
    const ushort_t* Wr, const ushort_t* Wz,
    const ushort_t* Wni, const ushort_t* Wnh,
    int ct, int rt0, int row_base, int lane, int l15, int q4)
{
    int col = ct*16 + l15;
    f32x4 ar[NR] = {}, az[NR] = {}, ani[NR] = {}, anh[NR] = {};
#pragma unroll 3
    for (int ks = 0; ks < 12; ks++) {
        bf16x8 wfr = wfragN(Wr, ct, 12, ks, lane);
        bf16x8 wfz = wfragN(Wz, ct, 12, ks, lane);
        bf16x8 wfn = (ks < 6) ? wfragN(Wni, ct, 6, ks, lane)
                              : wfragN(Wnh, ct, 6, ks - 6, lane);
#pragma unroll
        for (int r3 = 0; r3 < NR; r3++) {
            int rt = rt0 + r3;
            bf16x8 af = (ks < 6) ? ldsfrag(Rb, rt, ks, lane)
                                 : ldsfrag(hb, rt, ks - 6, lane);
            ar[r3] = __builtin_amdgcn_mfma_f32_16x16x32_bf16(af, wfr, ar[r3], 0,0,0);
            az[r3] = __builtin_amdgcn_mfma_f32_16x16x32_bf16(af, wfz, az[r3], 0,0,0);
            if (ks < 6)
                ani[r3] = __builtin_amdgcn_mfma_f32_16x16x32_bf16(af, wfn, ani[r3], 0,0,0);
            else
                anh[r3] = __builtin_amdgcn_mfma_f32_16x16x32_bf16(af, wfn, anh[r3], 0,0,0);
        }
    }
    float br  = biasfs[col]       + bhhs[col];
    float bz  = biasfs[col + 192] + bhhs[col + 192];
    float bni = biasfs[col + 384];
    float bnh = bhhs[col + 384];
#pragma unroll
    for (int r3 = 0; r3 < NR; r3++) {
#pragma unroll
        for (int i2 = 0; i2 < 4; i2++) {
            int row = (rt0 + r3)*16 + q4 + i2;
            bool ok = (row < 81);
            float hv = ok ? bf2f(hb[HBI(row, col)]) : 0.f;
            float rg = 1.f/(1.f + __expf(-(ar[r3][i2] + br)));
            float zg = 1.f/(1.f + __expf(-(az[r3][i2] + bz)));
            float e2 = __expf(2.f*(ani[r3][i2] + bni + rg*(anh[r3][i2] + bnh)));
            float ng = 1.f - 2.f/(e2 + 1.f);
            float v = (1.f - zg)*ng + zg*hv;
            if (!ok) v = 0.f;
            if (ok) hcf[HFI(row, col)] = v;
            float s = v, q2 = v*v;
#pragma unroll
            for (int m = 1; m < 16; m <<= 1) {
                s  += __shfl_xor(s, m);
                q2 += __shfl_xor(q2, m);
            }
            if (l15 == 0 && ok) spart[(row - row_base)*12 + ct] = make_float2(s, q2);
        }
    }
}

// ---------------------------------------------------------------------------
// r19 = r18 + Phase A wave rebalance: A1 = waves 0-5 x 2 A-cts (all 12 A
// cols -> publish timing unchanged) + waves 6-7 x 2 B-cts; A2 = exactly 1
// B-ct per wave. Every wave now carries 3 cts/step (was 4 on waves 0-3,
// 2 on waves 4-7) -> SYNC_A1 and the pull-barrier stop waiting on the
// overloaded waves. No math/layout/protocol change.
// ---------------------------------------------------------------------------
__global__ __launch_bounds__(512)
void k_main(const float* __restrict__ x, const float* __restrict__ W_in,
            const float* __restrict__ b_in, const float* __restrict__ g_in,
            const float* __restrict__ be_in, const float* __restrict__ pos,
            const float* __restrict__ b_m1, const float* __restrict__ g_n,
            const float* __restrict__ be_n, const float* __restrict__ b_hh,
            const float* __restrict__ b_out,
            const ushort_t* __restrict__ Wm1b, const ushort_t* __restrict__ Wr,
            const ushort_t* __restrict__ Wz, const ushort_t* __restrict__ Wni,
            const ushort_t* __restrict__ Wnh, const ushort_t* __restrict__ Woutb,
            const float* __restrict__ bias_f,
            ushort_t* __restrict__ Aex, int* __restrict__ ctr,
            float* __restrict__ out_all, float* __restrict__ out_last)
{
    extern __shared__ char smem[];
    ushort_t* Rb    = (ushort_t*)(smem);
    ushort_t* AB    = (ushort_t*)(smem + 31104);
    float*    hcf   = (float*)(smem + 31104);        // overlays AB
    ushort_t* hb    = (ushort_t*)(smem + 93312);
    float2*   spart = (float2*)(smem + 124416);      // [32][12] float2
    float* ssum   = (float*)(smem + 132192);
    float* ssq    = (float*)(smem + 132516);
    float* bm1s   = (float*)(smem + 132840);
    float* gns    = (float*)(smem + 133608);
    float* bens   = (float*)(smem + 134376);
    float* biasfs = (float*)(smem + 135144);
    float* bhhs   = (float*)(smem + 137448);

    const int tid = threadIdx.x;
    const int lane = tid & 63, wave = tid >> 6;      // wave in [0,8)
    const int l15 = lane & 15, q4 = (lane >> 4) << 2;
    const int g     = blockIdx.x & 63;               // graph
    const int third = blockIdx.x >> 6;               // 0,1,2 (partners +64)
    const int row_base = third * 32;
    const int nrows    = (third < 2) ? 32 : 17;
    const int rtb      = third * 2;                  // own rt pair

    if (tid < 192) { bm1s[tid] = b_m1[tid]; gns[tid] = g_n[tid]; bens[tid] = be_n[tid]; }
    for (int e = tid; e < 576; e += 512) { biasfs[e] = bias_f[e]; bhhs[e] = b_hh[e]; }

    // ---------------- h0 (own rows only; row-local) ----------------
    {
        float* xs = (float*)Rb;
        float* vf = hcf;
        for (int e = tid; e < nrows*10; e += 512) xs[e] = x[(size_t)g*810 + row_base*10 + e];
        __syncthreads();
        for (int e = tid; e < nrows*192; e += 512) {
            int nl = e / 192, j = e - nl*192;
            int n = row_base + nl;
            float v = b_in[j];
#pragma unroll
            for (int k = 0; k < 10; k++) v += xs[nl*10 + k] * W_in[k*192 + j];
            vf[n*192 + j] = v;
        }
        __syncthreads();
        if (tid < nrows*4) {
            int lr = tid >> 2, part = tid & 3;
            int row = row_base + lr;
            float s = 0.f, q = 0.f;
#pragma unroll
            for (int i = 0; i < 12; i++) {
                float4 v = *(float4*)&vf[row*192 + part*48 + i*4];
                s += v.x + v.y + v.z + v.w;
                q += v.x*v.x + v.y*v.y + v.z*v.z + v.w*v.w;
            }
            spart[tid] = make_float2(s, q);
        }
        __syncthreads();
        if (tid < nrows) {
            float2 p0 = spart[tid*4], p1 = spart[tid*4+1], p2 = spart[tid*4+2], p3 = spart[tid*4+3];
            float s = p0.x+p1.x+p2.x+p3.x, q = p0.y+p1.y+p2.y+p3.y;
            float m = s * (1.f/192.f);
            float var = q * (1.f/192.f) - m*m;
            ssum[row_base + tid] = m; ssq[row_base + tid] = rsqrtf(var + 1e-5f);
        }
        __syncthreads();
        for (int e = tid; e < nrows*192; e += 512) {
            int nl = e / 192, j = e - nl*192;
            int n = row_base + nl;
            float v = vf[n*192 + j];
            v = (v - ssum[n]) * ssq[n] * g_in[j] + be_in[j] + pos[n*192 + j];
            hb[HBI(n, j)] = f2bf(v);
        }
        __syncthreads();
    }

    for (int t = 0; t < NSTEPS; t++) {
        ushort_t* aex = Aex + ((size_t)(g*2 + (t & 1))) * 81 * 192;

        // ===== Phase A1 (balanced): waves 0-5 -> 2 A-cts; waves 6-7 -> 2 B =
#pragma unroll
        for (int c = 0; c < 2; c++) {
            int ct = (wave < 6) ? (wave*2 + c) : (12 + (wave - 6)*2 + c);
            bf16x8 wbc[6];
#pragma unroll
            for (int ks = 0; ks < 6; ks++)
                wbc[ks] = wfragN(Wm1b, ct, 6, ks, lane);
            int col = ct*16 + l15;
            float addb = (col >= 192) ? bm1s[col - 192] : 0.f;
#pragma unroll
            for (int r3 = 0; r3 < 2; r3++) {
                int rt = rtb + r3;
                f32x4 acc = {0.f, 0.f, 0.f, 0.f};
#pragma unroll
                for (int ks = 0; ks < 6; ks++)
                    acc = __builtin_amdgcn_mfma_f32_16x16x32_bf16(ldsfrag(hb, rt, ks, lane), wbc[ks], acc, 0, 0, 0);
#pragma unroll
                for (int i2 = 0; i2 < 4; i2++) {
                    int row = rt*16 + q4 + i2;
                    if (row < 81) AB[ABI(row, col)] = f2bf(acc[i2] + addb);
                }
            }
        }
        __syncthreads();   // SYNC_A1 (all 12 A cols complete in LDS)

        // ===== publish own A rows, vectorized =====
        for (int c = tid; c < nrows*24; c += 512) {
            int row = row_base + c / 24;
            int j0 = (c - (c/24)*24) * 8;
            *(us8*)&aex[row*192 + j0] = *(const us8*)&AB[ABI(row, j0)];
        }
        __syncthreads();   // publish stores drained
        if (tid == 0) {
            __threadfence();                       // release
            atomicAdd(&ctr[g], 1);                 // POST EARLY
        }

        // ===== Phase A2: one remaining B-ct per wave (cts 16-23) =====
        {
            int ct = 16 + wave;
            bf16x8 wbc[6];
#pragma unroll
            for (int ks = 0; ks < 6; ks++)
                wbc[ks] = wfragN(Wm1b, ct, 6, ks, lane);
            int col = ct*16 + l15;
            float addb = bm1s[col - 192];
#pragma unroll
            for (int r3 = 0; r3 < 2; r3++) {
                int rt = rtb + r3;
                f32x4 acc = {0.f, 0.f, 0.f, 0.f};
#pragma unroll
                for (int ks = 0; ks < 6; ks++)
                    acc = __builtin_amdgcn_mfma_f32_16x16x32_bf16(ldsfrag(hb, rt, ks, lane), wbc[ks], acc, 0, 0, 0);
#pragma unroll
                for (int i2 = 0; i2 < 4; i2++) {
                    int row = rt*16 + q4 + i2;
                    if (row < 81) AB[ABI(row, col)] = f2bf(acc[i2] + addb);
                }
            }
        }
        // (no SYNC here: tid0's spin is independent of other waves' A2)
        if (tid == 0) {
            int target = 3*(t + 1);
            while (atomicAdd(&ctr[g], 0) < target) __builtin_amdgcn_s_sleep(2);
            __threadfence();                       // acquire
        }
        __syncthreads();   // all waves done A2 AND tid0 observed counter
        // ===== pull partner A rows into LDS =====
        for (int c = tid; c < 81*24; c += 512) {
            int row = c / 24;
            if (row >= row_base && row < row_base + nrows) continue;
            int j0 = (c - row*24) * 8;
            *(us8*)&AB[ABI(row, j0)] = *(const us8*)&aex[row*192 + j0];
        }
        __syncthreads();   // SYNC_X (full A + own B now in LDS)

        // ===== Phase B: own dst rows =====
        for (int e = tid; e < nrows*24; e += 512) {
            int d = row_base + e / 24;
            int j0 = (e - (e/24)*24) * 8;
            float bsum[8], r8[8] = {0,0,0,0,0,0,0,0};
            us8 bu = *(const us8*)&AB[ABI(d, 192 + j0)];
#pragma unroll
            for (int i = 0; i < 8; i++) bsum[i] = bf2f(bu[i]);
            int rr = d / 9, cc = d - rr*9;
            int rb0 = (rr/3)*3, cb0 = (cc/3)*3;
#pragma unroll
            for (int c2 = 0; c2 < 9; c2++) {
                if (c2 == cc) continue;
                us8 au = *(const us8*)&AB[ABI(rr*9 + c2, j0)];
#pragma unroll
                for (int i = 0; i < 8; i++) r8[i] += fmaxf(bf2f(au[i]) + bsum[i], 0.f);
            }
#pragma unroll
            for (int r2 = 0; r2 < 9; r2++) {
                if (r2 == rr) continue;
                us8 au = *(const us8*)&AB[ABI(r2*9 + cc, j0)];
#pragma unroll
                for (int i = 0; i < 8; i++) r8[i] += fmaxf(bf2f(au[i]) + bsum[i], 0.f);
            }
#pragma unroll
            for (int r2 = 0; r2 < 3; r2++) {
                int rrr = rb0 + r2;
                if (rrr == rr) continue;
#pragma unroll
                for (int c2 = 0; c2 < 3; c2++) {
                    int ccc = cb0 + c2;
                    if (ccc == cc) continue;
                    us8 au = *(const us8*)&AB[ABI(rrr*9 + ccc, j0)];
#pragma unroll
                    for (int i = 0; i < 8; i++) r8[i] += fmaxf(bf2f(au[i]) + bsum[i], 0.f);
                }
            }
            us8 w;
#pragma unroll
            for (int i = 0; i < 8; i++) w[i] = f2bf(r8[i]);
            *(us8*)&Rb[HBI(d, j0)] = w;
        }
        __syncthreads();   // SYNC_B  (AB dead; hcf overlays it)

        // ===== Phase C (+fused LN partials): own 2 rt =====
        gru_unit<2>(Rb, hb, hcf, spart, biasfs, bhhs, Wr, Wz, Wni, Wnh,
                    wave, rtb, row_base, lane, l15, q4);
        gru_unit<1>(Rb, hb, hcf, spart, biasfs, bhhs, Wr, Wz, Wni, Wnh,
                    8 + (wave >> 1), rtb + (wave & 1), row_base, lane, l15, q4);
        __syncthreads();   // SYNC_C (hcf + all spart partials complete)

        // ===== LN stats final reduce =====
        if (tid < nrows) {
            float s = 0.f, q = 0.f;
#pragma unroll
            for (int i = 0; i < 12; i++) {
                float2 p = spart[tid*12 + i];
                s += p.x; q += p.y;
            }
            float m = s * (1.f/192.f);
            float var = q * (1.f/192.f) - m*m;
            ssum[row_base + tid] = m; ssq[row_base + tid] = rsqrtf(var + 1e-5f);
        }
        __syncthreads();   // SYNC_S

        // ===== Phase D: LayerNorm -> new h (own rows) =====
        for (int e = tid; e < nrows*192; e += 512) {
            int nl = e / 192, j = e - nl*192;
            int n = row_base + nl;
            float hc = hcf[HFI(n, j)];
            float hn2 = (hc - ssum[n]) * ssq[n] * gns[j] + bens[j];
            hb[HBI(n, j)] = f2bf(hn2);
        }
        __syncthreads();   // SYNC_D

        // ===== Phase E: logits (own 2 row-tiles on waves 0-1) =====
        if (wave < 2) {
            int rt = rtb + wave;
            f32x4 acc = {0.f, 0.f, 0.f, 0.f};
#pragma unroll
            for (int ks = 0; ks < 6; ks++) {
                bf16x8 ha = ldsfrag(hb, rt, ks, lane);
                acc = __builtin_amdgcn_mfma_f32_16x16x32_bf16(ha, wfragN(Woutb, 0, 6, ks, lane), acc, 0,0,0);
            }
            if (l15 < 9) {
                float bo = b_out[l15];
#pragma unroll
                for (int i2 = 0; i2 < 4; i2++) {
                    int row = rt*16 + q4 + i2;
                    if (row < 81) {
                        float v = acc[i2] + bo;
                        out_all[((size_t)t*NNODES + (size_t)g*81 + row)*9 + l15] = v;
                        if (t == NSTEPS-1)
                            out_last[((size_t)g*81 + row)*9 + l15] = v;
                    }
                }
            }
        }
    }
}

// ---------------------------------------------------------------------------
extern "C" void kernel_launch(void* const* d_in, const int* in_sizes, int n_in,
                              void* d_out, int out_size, void* d_ws, size_t ws_size,
                              hipStream_t stream) {
    const float* x     = (const float*)d_in[0];
    const float* W_in  = (const float*)d_in[2];
    const float* b_in  = (const float*)d_in[3];
    const float* g_in  = (const float*)d_in[4];
    const float* be_in = (const float*)d_in[5];
    const float* pos   = (const float*)d_in[6];
    const float* W_m1  = (const float*)d_in[7];
    const float* b_m1  = (const float*)d_in[8];
    const float* W_m2  = (const float*)d_in[9];
    const float* b_m2  = (const float*)d_in[10];
    const float* W_ih  = (const float*)d_in[11];
    const float* W_hh  = (const float*)d_in[12];
    const float* b_ih  = (const float*)d_in[13];
    const float* b_hh  = (const float*)d_in[14];
    const float* g_n   = (const float*)d_in[15];
    const float* be_n  = (const float*)d_in[16];
    const float* W_out = (const float*)d_in[17];
    const float* b_out = (const float*)d_in[18];

    char* ws = (char*)d_ws;
    float*    Wfused = (float*)ws;                   // 442368
    ushort_t* Wm1b   = (ushort_t*)(ws + 442368);     // 147456
    ushort_t* Wr     = (ushort_t*)(ws + 589824);     // 147456
    ushort_t* Wz     = (ushort_t*)(ws + 737280);     // 147456
    ushort_t* Wni    = (ushort_t*)(ws + 884736);     // 73728
    ushort_t* Wnh    = (ushort_t*)(ws + 958464);     // 73728
    ushort_t* Woutb  = (ushort_t*)(ws + 1032192);    // 6144
    float*    bias_f = (float*)(ws + 1038336);       // 2304
    ushort_t* Aex    = (ushort_t*)(ws + 1048576);    // 64*2*81*192*2B
    int*      ctr    = (int*)(ws + 5242880);         // 64 ints

    float* out_last = (float*)d_out;                 // (5184, 9)
    float* out_all  = (float*)d_out + NNODES*9;      // (16, 5184, 9)

    k_gemm<true><<<dim3(3, 9), 256, 0, stream>>>(W_m2, W_ih, nullptr, 0.f, Wfused, 576);
    k_prep<<<(298560 + 255)/256, 256, 0, stream>>>(W_m1, Wfused, W_hh, W_out, W_ih, b_m2, b_ih,
                                                   Wm1b, Wr, Wz, Wni, Wnh, Woutb, bias_f);
    k_zero<<<1, 64, 0, stream>>>(ctr);

    const int LDS_BYTES = 139752;
    hipFuncSetAttribute(reinterpret_cast<const void*>(k_main),
                        hipFuncAttributeMaxDynamicSharedMemorySize, LDS_BYTES);

    void* args[] = {
        (void*)&x, (void*)&W_in, (void*)&b_in, (void*)&g_in, (void*)&be_in,
        (void*)&pos, (void*)&b_m1, (void*)&g_n, (void*)&be_n, (void*)&b_hh,
        (void*)&b_out, (void*)&Wm1b, (void*)&Wr, (void*)&Wz, (void*)&Wni,
        (void*)&Wnh, (void*)&Woutb, (void*)&bias_f, (void*)&Aex, (void*)&ctr,
        (void*)&out_all, (void*)&out_last
    };
    hipLaunchCooperativeKernel(reinterpret_cast<const void*>(k_main),
                               dim3(192), dim3(512), args, LDS_BYTES, stream);
}

// Round 20
// 547.294 us; speedup vs baseline: 1.0818x; 1.0818x over previous
//
#include <hip/hip_runtime.h>
#include <hip/hip_bf16.h>
#include <math.h>

#define HID 192
#define NNODES 5184
#define NSTEPS 16

typedef float f32x4 __attribute__((ext_vector_type(4)));
typedef __bf16 bf16x8 __attribute__((ext_vector_type(8)));
typedef unsigned short ushort_t;
typedef ushort_t us8 __attribute__((ext_vector_type(8)));

__device__ __forceinline__ ushort_t f2bf(float f){
    __hip_bfloat16 h = __float2bfloat16(f);
    return __builtin_bit_cast(ushort_t, h);
}
__device__ __forceinline__ float bf2f(ushort_t u){
    return __uint_as_float(((unsigned)u) << 16);
}

#define HFI(r,c) ((r)*192 + ((c) ^ (((r)&7)<<2)))   // f32 buffer [81][192]
#define ABI(r,c) ((r)*384 + ((c) ^ (((r)&7)<<3)))   // bf16 buffer [81][384]
#define HBI(r,c) ((r)*192 + ((c) ^ (((r)&7)<<3)))   // bf16 buffer [81][192]

__device__ __forceinline__ bf16x8 ldsfrag(const ushort_t* buf, int rt, int ks, int lane){
    int r = rt*16 + (lane & 15);
    int k0 = ks*32 + ((lane >> 4) << 3);
    if (r < 81) return *(const bf16x8*)&buf[HBI(r, k0)];
    us8 z = {0,0,0,0,0,0,0,0};
    return __builtin_bit_cast(bf16x8, z);
}
__device__ __forceinline__ bf16x8 wfragN(const ushort_t* W, int ct, int nks, int ks, int lane){
    return *(const bf16x8*)&W[(size_t)(((ct*nks) + ks)*64 + lane)*8];
}

// ---------------------------------------------------------------------------
template <bool TRANSB>
__global__ __launch_bounds__(256)
void k_gemm(const float* __restrict__ A, const float* __restrict__ B,
            const float* __restrict__ bias, float biasScale,
            float* __restrict__ C, int N) {
    const int K = HID;
    __shared__ float As[64][17];
    __shared__ float Bs[16][65];
    int tid = threadIdx.x;
    int tx = tid & 15, ty = tid >> 4;
    int rowBase = blockIdx.x * 64;
    int colBase = blockIdx.y * 64;
    float acc[4][4] = {};
    for (int k0 = 0; k0 < K; k0 += 16) {
        {
            int r = tid >> 2, kk = (tid & 3) << 2;
            const float4 av = *(const float4*)&A[(size_t)(rowBase + r) * K + k0 + kk];
            As[r][kk + 0] = av.x; As[r][kk + 1] = av.y;
            As[r][kk + 2] = av.z; As[r][kk + 3] = av.w;
        }
        if (!TRANSB) {
            int kk = tid >> 4, j4 = (tid & 15) << 2;
            const float4 bv = *(const float4*)&B[(size_t)(k0 + kk) * N + colBase + j4];
            Bs[kk][j4 + 0] = bv.x; Bs[kk][j4 + 1] = bv.y;
            Bs[kk][j4 + 2] = bv.z; Bs[kk][j4 + 3] = bv.w;
        } else {
            int jj = tid >> 2, kk = (tid & 3) << 2;
            const float4 bv = *(const float4*)&B[(size_t)(colBase + jj) * K + k0 + kk];
            Bs[kk + 0][jj] = bv.x; Bs[kk + 1][jj] = bv.y;
            Bs[kk + 2][jj] = bv.z; Bs[kk + 3][jj] = bv.w;
        }
        __syncthreads();
#pragma unroll
        for (int kk = 0; kk < 16; kk++) {
            float a0 = As[ty*4+0][kk], a1 = As[ty*4+1][kk];
            float a2 = As[ty*4+2][kk], a3 = As[ty*4+3][kk];
            float b0 = Bs[kk][tx*4+0], b1 = Bs[kk][tx*4+1];
            float b2 = Bs[kk][tx*4+2], b3 = Bs[kk][tx*4+3];
            acc[0][0]+=a0*b0; acc[0][1]+=a0*b1; acc[0][2]+=a0*b2; acc[0][3]+=a0*b3;
            acc[1][0]+=a1*b0; acc[1][1]+=a1*b1; acc[1][2]+=a1*b2; acc[1][3]+=a1*b3;
            acc[2][0]+=a2*b0; acc[2][1]+=a2*b1; acc[2][2]+=a2*b2; acc[2][3]+=a2*b3;
            acc[3][0]+=a3*b0; acc[3][1]+=a3*b1; acc[3][2]+=a3*b2; acc[3][3]+=a3*b3;
        }
        __syncthreads();
    }
    float4 bb = make_float4(0.f,0.f,0.f,0.f);
    if (bias) {
        bb = *(const float4*)&bias[colBase + tx*4];
        bb.x*=biasScale; bb.y*=biasScale; bb.z*=biasScale; bb.w*=biasScale;
    }
#pragma unroll
    for (int i = 0; i < 4; i++) {
        int r = rowBase + ty*4 + i;
        float4 o;
        o.x=acc[i][0]+bb.x; o.y=acc[i][1]+bb.y; o.z=acc[i][2]+bb.z; o.w=acc[i][3]+bb.w;
        *(float4*)&C[(size_t)r * N + colBase + tx*4] = o;
    }
}

// ---------------------------------------------------------------------------
__global__ void k_prep(const float* __restrict__ W_m1, const float* __restrict__ Wfused,
                       const float* __restrict__ W_hh, const float* __restrict__ W_out,
                       const float* __restrict__ W_ih, const float* __restrict__ b_m2,
                       const float* __restrict__ b_ih,
                       ushort_t* __restrict__ Wm1b, ushort_t* __restrict__ Wr,
                       ushort_t* __restrict__ Wz, ushort_t* __restrict__ Wni,
                       ushort_t* __restrict__ Wnh, ushort_t* __restrict__ Woutb,
                       float* __restrict__ bias_f) {
    int t = blockIdx.x * 256 + threadIdx.x;
    const int n0 = 73728;
    const int n1 = n0 + 73728;
    const int n2 = n1 + 73728;
    const int n3 = n2 + 36864;
    const int n4 = n3 + 36864;
    const int n5 = n4 + 3072;
    const int n6 = n5 + 576;
    if (t < n0) {
        int idx = t;
        int e = idx & 7, lane = (idx >> 3) & 63, cs = idx >> 9;
        int ct = cs / 6, ks = cs - ct*6;
        int k = ks*32 + ((lane>>4)<<3) + e, col = ct*16 + (lane & 15);
        float v = (col < 192) ? W_m1[k*192 + col] : W_m1[(192 + k)*192 + (col - 192)];
        Wm1b[idx] = f2bf(v);
    } else if (t < n1) {
        int idx = t - n0;
        int e = idx & 7, lane = (idx >> 3) & 63, cs = idx >> 9;
        int ct = cs / 12, ks = cs - ct*12;
        int k = ks*32 + ((lane>>4)<<3) + e, col = ct*16 + (lane & 15);
        float v = (k < 192) ? Wfused[k*576 + col] : W_hh[col*192 + (k - 192)];
        Wr[idx] = f2bf(v);
    } else if (t < n2) {
        int idx = t - n1;
        int e = idx & 7, lane = (idx >> 3) & 63, cs = idx >> 9;
        int ct = cs / 12, ks = cs - ct*12;
        int k = ks*32 + ((lane>>4)<<3) + e, col = ct*16 + (lane & 15);
        float v = (k < 192) ? Wfused[k*576 + 192 + col] : W_hh[(192 + col)*192 + (k - 192)];
        Wz[idx] = f2bf(v);
    } else if (t < n3) {
        int idx = t - n2;
        int e = idx & 7, lane = (idx >> 3) & 63, cs = idx >> 9;
        int ct = cs / 6, ks = cs - ct*6;
        int k = ks*32 + ((lane>>4)<<3) + e, col = ct*16 + (lane & 15);
        Wni[idx] = f2bf(Wfused[k*576 + 384 + col]);
    } else if (t < n4) {
        int idx = t - n3;
        int e = idx & 7, lane = (idx >> 3) & 63, cs = idx >> 9;
        int ct = cs / 6, ks = cs - ct*6;
        int k = ks*32 + ((lane>>4)<<3) + e, col = ct*16 + (lane & 15);
        Wnh[idx] = f2bf(W_hh[(384 + col)*192 + k]);
    } else if (t < n5) {
        int idx = t - n4;
        int e = idx & 7, lane = (idx >> 3) & 63, ks = idx >> 9;
        int k = ks*32 + ((lane>>4)<<3) + e, col = lane & 15;
        Woutb[idx] = (col < 9) ? f2bf(W_out[k*9 + col]) : (ushort_t)0;
    } else if (t < n6) {
        int n = t - n5;
        float s = 0.f;
        for (int m = 0; m < 192; m++) s += b_m2[m] * W_ih[n*192 + m];
        bias_f[n] = 20.f * s + b_ih[n];
    }
}

__global__ void k_zero(int* p){ p[threadIdx.x] = 0; }

// GRU unit with fused LN partial stats (16-lane shfl, transient regs only).
template<int NR>
__device__ __forceinline__ void gru_unit(
    const ushort_t* Rb, const ushort_t* hb, float* hcf, float2* spart,
    const float* biasfs, const float* bhhs,
    const ushort_t* Wr, const ushort_t* Wz,
    const ushort_t* Wni, const ushort_t* Wnh,
    int ct, int rt0, int row_base, int lane, int l15, int q4)
{
    int col = ct*16 + l15;
    f32x4 ar[NR] = {}, az[NR] = {}, ani[NR] = {}, anh[NR] = {};
#pragma unroll 3
    for (int ks = 0; ks < 12; ks++) {
        bf16x8 wfr = wfragN(Wr, ct, 12, ks, lane);
        bf16x8 wfz = wfragN(Wz, ct, 12, ks, lane);
        bf16x8 wfn = (ks < 6) ? wfragN(Wni, ct, 6, ks, lane)
                              : wfragN(Wnh, ct, 6, ks - 6, lane);
#pragma unroll
        for (int r3 = 0; r3 < NR; r3++) {
            int rt = rt0 + r3;
            bf16x8 af = (ks < 6) ? ldsfrag(Rb, rt, ks, lane)
                                 : ldsfrag(hb, rt, ks - 6, lane);
            ar[r3] = __builtin_amdgcn_mfma_f32_16x16x32_bf16(af, wfr, ar[r3], 0,0,0);
            az[r3] = __builtin_amdgcn_mfma_f32_16x16x32_bf16(af, wfz, az[r3], 0,0,0);
            if (ks < 6)
                ani[r3] = __builtin_amdgcn_mfma_f32_16x16x32_bf16(af, wfn, ani[r3], 0,0,0);
            else
                anh[r3] = __builtin_amdgcn_mfma_f32_16x16x32_bf16(af, wfn, anh[r3], 0,0,0);
        }
    }
    float br  = biasfs[col]       + bhhs[col];
    float bz  = biasfs[col + 192] + bhhs[col + 192];
    float bni = biasfs[col + 384];
    float bnh = bhhs[col + 384];
#pragma unroll
    for (int r3 = 0; r3 < NR; r3++) {
#pragma unroll
        for (int i2 = 0; i2 < 4; i2++) {
            int row = (rt0 + r3)*16 + q4 + i2;
            bool ok = (row < 81);
            float hv = ok ? bf2f(hb[HBI(row, col)]) : 0.f;
            float rg = 1.f/(1.f + __expf(-(ar[r3][i2] + br)));
            float zg = 1.f/(1.f + __expf(-(az[r3][i2] + bz)));
            float e2 = __expf(2.f*(ani[r3][i2] + bni + rg*(anh[r3][i2] + bnh)));
            float ng = 1.f - 2.f/(e2 + 1.f);
            float v = (1.f - zg)*ng + zg*hv;
            if (!ok) v = 0.f;
            if (ok) hcf[HFI(row, col)] = v;
            float s = v, q2 = v*v;
#pragma unroll
            for (int m = 1; m < 16; m <<= 1) {
                s  += __shfl_xor(s, m);
                q2 += __shfl_xor(q2, m);
            }
            if (l15 == 0 && ok) spart[(row - row_base)*12 + ct] = make_float2(s, q2);
        }
    }
}

// ---------------------------------------------------------------------------
// FINAL (= r18, the best verified configuration @549 us):
// 3-way cooperative split (192 blocks, XCD-paired exchange at stride 64),
// Phase A split A1/A2 with early counter post (exchange latency hidden
// under B-column compute), vectorized LDS->global publish, LN partial
// stats fused into Phase C via transient shfl. 8 barriers/step.
// r19's rebalance regressed (VGPR 120->128, spill WRITE +14MB): at this
// register envelope, added per-wave addressing state costs more than the
// phase imbalance it removes.
// ---------------------------------------------------------------------------
__global__ __launch_bounds__(512)
void k_main(const float* __restrict__ x, const float* __restrict__ W_in,
            const float* __restrict__ b_in, const float* __restrict__ g_in,
            const float* __restrict__ be_in, const float* __restrict__ pos,
            const float* __restrict__ b_m1, const float* __restrict__ g_n,
            const float* __restrict__ be_n, const float* __restrict__ b_hh,
            const float* __restrict__ b_out,
            const ushort_t* __restrict__ Wm1b, const ushort_t* __restrict__ Wr,
            const ushort_t* __restrict__ Wz, const ushort_t* __restrict__ Wni,
            const ushort_t* __restrict__ Wnh, const ushort_t* __restrict__ Woutb,
            const float* __restrict__ bias_f,
            ushort_t* __restrict__ Aex, int* __restrict__ ctr,
            float* __restrict__ out_all, float* __restrict__ out_last)
{
    extern __shared__ char smem[];
    ushort_t* Rb    = (ushort_t*)(smem);
    ushort_t* AB    = (ushort_t*)(smem + 31104);
    float*    hcf   = (float*)(smem + 31104);        // overlays AB
    ushort_t* hb    = (ushort_t*)(smem + 93312);
    float2*   spart = (float2*)(smem + 124416);      // [32][12] float2
    float* ssum   = (float*)(smem + 132192);
    float* ssq    = (float*)(smem + 132516);
    float* bm1s   = (float*)(smem + 132840);
    float* gns    = (float*)(smem + 133608);
    float* bens   = (float*)(smem + 134376);
    float* biasfs = (float*)(smem + 135144);
    float* bhhs   = (float*)(smem + 137448);

    const int tid = threadIdx.x;
    const int lane = tid & 63, wave = tid >> 6;      // wave in [0,8)
    const int l15 = lane & 15, q4 = (lane >> 4) << 2;
    const int g     = blockIdx.x & 63;               // graph
    const int third = blockIdx.x >> 6;               // 0,1,2 (partners +64)
    const int row_base = third * 32;
    const int nrows    = (third < 2) ? 32 : 17;
    const int rtb      = third * 2;                  // own rt pair

    if (tid < 192) { bm1s[tid] = b_m1[tid]; gns[tid] = g_n[tid]; bens[tid] = be_n[tid]; }
    for (int e = tid; e < 576; e += 512) { biasfs[e] = bias_f[e]; bhhs[e] = b_hh[e]; }

    // ---------------- h0 (own rows only; row-local) ----------------
    {
        float* xs = (float*)Rb;
        float* vf = hcf;
        for (int e = tid; e < nrows*10; e += 512) xs[e] = x[(size_t)g*810 + row_base*10 + e];
        __syncthreads();
        for (int e = tid; e < nrows*192; e += 512) {
            int nl = e / 192, j = e - nl*192;
            int n = row_base + nl;
            float v = b_in[j];
#pragma unroll
            for (int k = 0; k < 10; k++) v += xs[nl*10 + k] * W_in[k*192 + j];
            vf[n*192 + j] = v;
        }
        __syncthreads();
        if (tid < nrows*4) {
            int lr = tid >> 2, part = tid & 3;
            int row = row_base + lr;
            float s = 0.f, q = 0.f;
#pragma unroll
            for (int i = 0; i < 12; i++) {
                float4 v = *(float4*)&vf[row*192 + part*48 + i*4];
                s += v.x + v.y + v.z + v.w;
                q += v.x*v.x + v.y*v.y + v.z*v.z + v.w*v.w;
            }
            spart[tid] = make_float2(s, q);
        }
        __syncthreads();
        if (tid < nrows) {
            float2 p0 = spart[tid*4], p1 = spart[tid*4+1], p2 = spart[tid*4+2], p3 = spart[tid*4+3];
            float s = p0.x+p1.x+p2.x+p3.x, q = p0.y+p1.y+p2.y+p3.y;
            float m = s * (1.f/192.f);
            float var = q * (1.f/192.f) - m*m;
            ssum[row_base + tid] = m; ssq[row_base + tid] = rsqrtf(var + 1e-5f);
        }
        __syncthreads();
        for (int e = tid; e < nrows*192; e += 512) {
            int nl = e / 192, j = e - nl*192;
            int n = row_base + nl;
            float v = vf[n*192 + j];
            v = (v - ssum[n]) * ssq[n] * g_in[j] + be_in[j] + pos[n*192 + j];
            hb[HBI(n, j)] = f2bf(v);
        }
        __syncthreads();
    }

    for (int t = 0; t < NSTEPS; t++) {
        ushort_t* aex = Aex + ((size_t)(g*2 + (t & 1))) * 81 * 192;

        // ===== Phase A1: A col-tiles (cts 0-11), waves strided =====
        for (int ct = wave; ct < 12; ct += 8) {
            bf16x8 wbc[6];
#pragma unroll
            for (int ks = 0; ks < 6; ks++)
                wbc[ks] = wfragN(Wm1b, ct, 6, ks, lane);
            int col = ct*16 + l15;
#pragma unroll
            for (int r3 = 0; r3 < 2; r3++) {
                int rt = rtb + r3;
                f32x4 acc = {0.f, 0.f, 0.f, 0.f};
#pragma unroll
                for (int ks = 0; ks < 6; ks++)
                    acc = __builtin_amdgcn_mfma_f32_16x16x32_bf16(ldsfrag(hb, rt, ks, lane), wbc[ks], acc, 0, 0, 0);
#pragma unroll
                for (int i2 = 0; i2 < 4; i2++) {
                    int row = rt*16 + q4 + i2;
                    if (row < 81) AB[ABI(row, col)] = f2bf(acc[i2]);
                }
            }
        }
        __syncthreads();   // SYNC_A1 (A half complete in LDS)

        // ===== publish own A rows, vectorized =====
        for (int c = tid; c < nrows*24; c += 512) {
            int row = row_base + c / 24;
            int j0 = (c - (c/24)*24) * 8;
            *(us8*)&aex[row*192 + j0] = *(const us8*)&AB[ABI(row, j0)];
        }
        __syncthreads();   // publish stores drained
        if (tid == 0) {
            __threadfence();                       // release
            atomicAdd(&ctr[g], 1);                 // POST EARLY
        }

        // ===== Phase A2: B col-tiles (cts 12-23) while partners publish ====
        for (int ct = 12 + wave; ct < 24; ct += 8) {
            bf16x8 wbc[6];
#pragma unroll
            for (int ks = 0; ks < 6; ks++)
                wbc[ks] = wfragN(Wm1b, ct, 6, ks, lane);
            int col = ct*16 + l15;
            float addb = bm1s[col - 192];
#pragma unroll
            for (int r3 = 0; r3 < 2; r3++) {
                int rt = rtb + r3;
                f32x4 acc = {0.f, 0.f, 0.f, 0.f};
#pragma unroll
                for (int ks = 0; ks < 6; ks++)
                    acc = __builtin_amdgcn_mfma_f32_16x16x32_bf16(ldsfrag(hb, rt, ks, lane), wbc[ks], acc, 0, 0, 0);
#pragma unroll
                for (int i2 = 0; i2 < 4; i2++) {
                    int row = rt*16 + q4 + i2;
                    if (row < 81) AB[ABI(row, col)] = f2bf(acc[i2] + addb);
                }
            }
        }
        // (no SYNC here: tid0's spin is independent of other waves' A2)
        if (tid == 0) {
            int target = 3*(t + 1);
            while (atomicAdd(&ctr[g], 0) < target) __builtin_amdgcn_s_sleep(2);
            __threadfence();                       // acquire
        }
        __syncthreads();   // all waves done A2 AND tid0 observed counter
        // ===== pull partner A rows into LDS =====
        for (int c = tid; c < 81*24; c += 512) {
            int row = c / 24;
            if (row >= row_base && row < row_base + nrows) continue;
            int j0 = (c - row*24) * 8;
            *(us8*)&AB[ABI(row, j0)] = *(const us8*)&aex[row*192 + j0];
        }
        __syncthreads();   // SYNC_X (full A + own B now in LDS)

        // ===== Phase B: own dst rows =====
        for (int e = tid; e < nrows*24; e += 512) {
            int d = row_base + e / 24;
            int j0 = (e - (e/24)*24) * 8;
            float bsum[8], r8[8] = {0,0,0,0,0,0,0,0};
            us8 bu = *(const us8*)&AB[ABI(d, 192 + j0)];
#pragma unroll
            for (int i = 0; i < 8; i++) bsum[i] = bf2f(bu[i]);
            int rr = d / 9, cc = d - rr*9;
            int rb0 = (rr/3)*3, cb0 = (cc/3)*3;
#pragma unroll
            for (int c2 = 0; c2 < 9; c2++) {
                if (c2 == cc) continue;
                us8 au = *(const us8*)&AB[ABI(rr*9 + c2, j0)];
#pragma unroll
                for (int i = 0; i < 8; i++) r8[i] += fmaxf(bf2f(au[i]) + bsum[i], 0.f);
            }
#pragma unroll
            for (int r2 = 0; r2 < 9; r2++) {
                if (r2 == rr) continue;
                us8 au = *(const us8*)&AB[ABI(r2*9 + cc, j0)];
#pragma unroll
                for (int i = 0; i < 8; i++) r8[i] += fmaxf(bf2f(au[i]) + bsum[i], 0.f);
            }
#pragma unroll
            for (int r2 = 0; r2 < 3; r2++) {
                int rrr = rb0 + r2;
                if (rrr == rr) continue;
#pragma unroll
                for (int c2 = 0; c2 < 3; c2++) {
                    int ccc = cb0 + c2;
                    if (ccc == cc) continue;
                    us8 au = *(const us8*)&AB[ABI(rrr*9 + ccc, j0)];
#pragma unroll
                    for (int i = 0; i < 8; i++) r8[i] += fmaxf(bf2f(au[i]) + bsum[i], 0.f);
                }
            }
            us8 w;
#pragma unroll
            for (int i = 0; i < 8; i++) w[i] = f2bf(r8[i]);
            *(us8*)&Rb[HBI(d, j0)] = w;
        }
        __syncthreads();   // SYNC_B  (AB dead; hcf overlays it)

        // ===== Phase C (+fused LN partials): own 2 rt =====
        gru_unit<2>(Rb, hb, hcf, spart, biasfs, bhhs, Wr, Wz, Wni, Wnh,
                    wave, rtb, row_base, lane, l15, q4);
        gru_unit<1>(Rb, hb, hcf, spart, biasfs, bhhs, Wr, Wz, Wni, Wnh,
                    8 + (wave >> 1), rtb + (wave & 1), row_base, lane, l15, q4);
        __syncthreads();   // SYNC_C (hcf + all spart partials complete)

        // ===== LN stats final reduce =====
        if (tid < nrows) {
            float s = 0.f, q = 0.f;
#pragma unroll
            for (int i = 0; i < 12; i++) {
                float2 p = spart[tid*12 + i];
                s += p.x; q += p.y;
            }
            float m = s * (1.f/192.f);
            float var = q * (1.f/192.f) - m*m;
            ssum[row_base + tid] = m; ssq[row_base + tid] = rsqrtf(var + 1e-5f);
        }
        __syncthreads();   // SYNC_S

        // ===== Phase D: LayerNorm -> new h (own rows) =====
        for (int e = tid; e < nrows*192; e += 512) {
            int nl = e / 192, j = e - nl*192;
            int n = row_base + nl;
            float hc = hcf[HFI(n, j)];
            float hn2 = (hc - ssum[n]) * ssq[n] * gns[j] + bens[j];
            hb[HBI(n, j)] = f2bf(hn2);
        }
        __syncthreads();   // SYNC_D

        // ===== Phase E: logits (own 2 row-tiles on waves 0-1) =====
        if (wave < 2) {
            int rt = rtb + wave;
            f32x4 acc = {0.f, 0.f, 0.f, 0.f};
#pragma unroll
            for (int ks = 0; ks < 6; ks++) {
                bf16x8 ha = ldsfrag(hb, rt, ks, lane);
                acc = __builtin_amdgcn_mfma_f32_16x16x32_bf16(ha, wfragN(Woutb, 0, 6, ks, lane), acc, 0,0,0);
            }
            if (l15 < 9) {
                float bo = b_out[l15];
#pragma unroll
                for (int i2 = 0; i2 < 4; i2++) {
                    int row = rt*16 + q4 + i2;
                    if (row < 81) {
                        float v = acc[i2] + bo;
                        out_all[((size_t)t*NNODES + (size_t)g*81 + row)*9 + l15] = v;
                        if (t == NSTEPS-1)
                            out_last[((size_t)g*81 + row)*9 + l15] = v;
                    }
                }
            }
        }
    }
}

// ---------------------------------------------------------------------------
extern "C" void kernel_launch(void* const* d_in, const int* in_sizes, int n_in,
                              void* d_out, int out_size, void* d_ws, size_t ws_size,
                              hipStream_t stream) {
    const float* x     = (const float*)d_in[0];
    const float* W_in  = (const float*)d_in[2];
    const float* b_in  = (const float*)d_in[3];
    const float* g_in  = (const float*)d_in[4];
    const float* be_in = (const float*)d_in[5];
    const float* pos   = (const float*)d_in[6];
    const float* W_m1  = (const float*)d_in[7];
    const float* b_m1  = (const float*)d_in[8];
    const float* W_m2  = (const float*)d_in[9];
    const float* b_m2  = (const float*)d_in[10];
    const float* W_ih  = (const float*)d_in[11];
    const float* W_hh  = (const float*)d_in[12];
    const float* b_ih  = (const float*)d_in[13];
    const float* b_hh  = (const float*)d_in[14];
    const float* g_n   = (const float*)d_in[15];
    const float* be_n  = (const float*)d_in[16];
    const float* W_out = (const float*)d_in[17];
    const float* b_out = (const float*)d_in[18];

    char* ws = (char*)d_ws;
    float*    Wfused = (float*)ws;                   // 442368
    ushort_t* Wm1b   = (ushort_t*)(ws + 442368);     // 147456
    ushort_t* Wr     = (ushort_t*)(ws + 589824);     // 147456
    ushort_t* Wz     = (ushort_t*)(ws + 737280);     // 147456
    ushort_t* Wni    = (ushort_t*)(ws + 884736);     // 73728
    ushort_t* Wnh    = (ushort_t*)(ws + 958464);     // 73728
    ushort_t* Woutb  = (ushort_t*)(ws + 1032192);    // 6144
    float*    bias_f = (float*)(ws + 1038336);       // 2304
    ushort_t* Aex    = (ushort_t*)(ws + 1048576);    // 64*2*81*192*2B
    int*      ctr    = (int*)(ws + 5242880);         // 64 ints

    float* out_last = (float*)d_out;                 // (5184, 9)
    float* out_all  = (float*)d_out + NNODES*9;      // (16, 5184, 9)

    k_gemm<true><<<dim3(3, 9), 256, 0, stream>>>(W_m2, W_ih, nullptr, 0.f, Wfused, 576);
    k_prep<<<(298560 + 255)/256, 256, 0, stream>>>(W_m1, Wfused, W_hh, W_out, W_ih, b_m2, b_ih,
                                                   Wm1b, Wr, Wz, Wni, Wnh, Woutb, bias_f);
    k_zero<<<1, 64, 0, stream>>>(ctr);

    const int LDS_BYTES = 139752;
    hipFuncSetAttribute(reinterpret_cast<const void*>(k_main),
                        hipFuncAttributeMaxDynamicSharedMemorySize, LDS_BYTES);

    void* args[] = {
        (void*)&x, (void*)&W_in, (void*)&b_in, (void*)&g_in, (void*)&be_in,
        (void*)&pos, (void*)&b_m1, (void*)&g_n, (void*)&be_n, (void*)&b_hh,
        (void*)&b_out, (void*)&Wm1b, (void*)&Wr, (void*)&Wz, (void*)&Wni,
        (void*)&Wnh, (void*)&Woutb, (void*)&bias_f, (void*)&Aex, (void*)&ctr,
        (void*)&out_all, (void*)&out_last
    };
    hipLaunchCooperativeKernel(reinterpret_cast<const void*>(k_main),
                               dim3(192), dim3(512), args, LDS_BYTES, stream);
}